// Round 1
// baseline (63.550 us; speedup 1.0000x reference)
//
#include <hip/hip_runtime.h>
#include <math.h>

// ---------------------------------------------------------------------------
// SpikingColorVision: 4 pops x 8 ch Izhikevich RS neurons, 1000 Euler steps.
// Latency-bound single-wave problem. Kernel 1 transposes noise to
// neuron-major (so each lane streams contiguous float4); kernel 2 runs the
// whole simulation in one 64-lane wave with 16-step-deep load prefetch.
// FP32 expression trees mirror the JAX reference exactly; FMA contraction is
// disabled to match XLA CPU's separate mul/add codegen.
// ---------------------------------------------------------------------------

// One Euler substep; matches reference op-for-op (DT=1 multiplies elided,
// they are exact). Uses v,u,rate,Ib from enclosing scope.
#define STEP(eps) do {                                   \
    float I_ = Ib + (eps) * 0.3f;                        \
    float q_ = 0.04f * v;                                \
    q_ = q_ * v;                                         \
    q_ = q_ + 5.0f * v;                                  \
    q_ = q_ + 140.0f;                                    \
    q_ = q_ - u;                                         \
    q_ = q_ + I_;                                        \
    float vn_ = v + q_;                                  \
    float un_ = u + 0.02f * (0.2f * v - u);              \
    bool  sp_ = (vn_ >= 30.0f);                          \
    float s_  = sp_ ? 1.0f : 0.0f;                       \
    v = sp_ ? -65.0f : vn_;                              \
    u = un_ + s_ * 8.0f;                                 \
    rate = 0.95f * rate + 0.05f * s_;                    \
  } while (0)

// Drives from the 800 retinal type values; every lane returns its own
// population's I_base. Counts are exact small integers -> reduction order
// is irrelevant (sums are exact in f32).
__device__ __forceinline__ float compute_Ib(const float* __restrict__ retL,
                                            const float* __restrict__ retR,
                                            int lane) {
#pragma clang fp contract(off)
  float f = 0.0f, e = 0.0f, r = 0.0f, cp = 0.0f;
  for (int i = lane; i < 800; i += 64) {
    float t = (i < 400) ? retL[i] : retR[i - 400];
    f  += (t > 0.7f) ? 1.0f : 0.0f;
    e  += (fabsf(t - 0.5f)  < 0.1f) ? 1.0f : 0.0f;
    r  += (fabsf(t - 0.75f) < 0.1f) ? 1.0f : 0.0f;
    cp += (fabsf(t - 0.25f) < 0.1f) ? 1.0f : 0.0f;
  }
#pragma unroll
  for (int off = 1; off < 64; off <<= 1) {
    f  += __shfl_xor(f,  off);
    e  += __shfl_xor(e,  off);
    r  += __shfl_xor(r,  off);
    cp += __shfl_xor(cp, off);
  }
  float total = f + e + r + cp + 1e-8f;  // same assoc order as reference
  int p = (lane >> 3) & 3;
  float dv;
  if (p == 0)      dv = (f * 0.1f + e * 0.05f + cp * 0.8f + r * 0.2f) / total;
  else if (p == 1) dv = (f * 0.2f + e * 0.1f  + cp * 0.5f + r * 0.3f) / total;
  else if (p == 2) dv = (f * 0.8f + e * 0.3f  + cp * 0.3f + r * 0.3f) / total;
  else             dv = (f * 0.4f + e * 0.7f  + cp * 0.2f + r * 0.3f) / total;
  return dv * 10.0f + (-2.0f);  // I_base = drives*10 + I_TONIC (+0)
}

// Channel means + opponency outputs; lane holds rate for neuron lane&31.
__device__ __forceinline__ void write_outputs(float rate, int lane,
                                              float* __restrict__ out) {
#pragma clang fp contract(off)
  float rsum = rate;
  rsum += __shfl_xor(rsum, 1);
  rsum += __shfl_xor(rsum, 2);
  rsum += __shfl_xor(rsum, 4);
  float mean = rsum / 8.0f;            // exact /8
  float m_uv = __shfl(mean, 0);
  float m_bl = __shfl(mean, 8);
  float m_gr = __shfl(mean, 16);
  float m_rd = __shfl(mean, 24);
  if (lane == 0) {
    out[0] = m_uv;
    out[1] = m_bl;
    out[2] = m_gr;
    out[3] = m_rd;
    out[4] = m_rd - m_gr;
    out[5] = (m_uv + m_bl) / 2.0f - (m_gr + m_rd) / 2.0f;
  }
}

// Transpose noise [S][32] -> noiseT [32][S+16] (16-float zero pad per neuron
// so the sim kernel's prefetch loads never go OOB). Coalesced writes.
__global__ void scv_transpose_kernel(const float* __restrict__ noise,
                                     float* __restrict__ noiseT, int S) {
  int stride = S + 16;
  int total = 32 * stride;
  for (int o = blockIdx.x * blockDim.x + threadIdx.x; o < total;
       o += gridDim.x * blockDim.x) {
    int n = o / stride;
    int t = o - n * stride;
    noiseT[o] = (t < S) ? noise[t * 32 + n] : 0.0f;
  }
}

// Main simulation: one block, one 64-lane wave. neuron = lane & 31
// (upper 32 lanes duplicate work to keep the wave uniform).
__global__ __launch_bounds__(64) void scv_sim_kernel(
    const float* __restrict__ retL, const float* __restrict__ retR,
    const float* __restrict__ noiseT, float* __restrict__ out, int S) {
#pragma clang fp contract(off)
  const int lane = threadIdx.x;
  float Ib = compute_Ib(retL, retR, lane);

  float v = -65.0f;
  float u = 0.2f * v;   // == -13.0f exactly, same as B*v0 in f32
  float rate = 0.0f;

  const int neuron = lane & 31;
  const int stride4 = (S + 16) >> 2;
  const float4* src =
      reinterpret_cast<const float4*>(noiseT) + (size_t)neuron * stride4;

  int nChunks = S >> 2;          // 4 steps per float4
  float4 b0 = src[0], b1 = src[1], b2 = src[2], b3 = src[3];
  int cG = nChunks & ~3;
  for (int c = 0; c < cG; c += 4) {
    STEP(b0.x); STEP(b0.y); STEP(b0.z); STEP(b0.w); b0 = src[c + 4];
    STEP(b1.x); STEP(b1.y); STEP(b1.z); STEP(b1.w); b1 = src[c + 5];
    STEP(b2.x); STEP(b2.y); STEP(b2.z); STEP(b2.w); b2 = src[c + 6];
    STEP(b3.x); STEP(b3.y); STEP(b3.z); STEP(b3.w); b3 = src[c + 7];
  }
  int rem = nChunks - cG;
  if (rem >= 1) { STEP(b0.x); STEP(b0.y); STEP(b0.z); STEP(b0.w); }
  if (rem >= 2) { STEP(b1.x); STEP(b1.y); STEP(b1.z); STEP(b1.w); }
  if (rem >= 3) { STEP(b2.x); STEP(b2.y); STEP(b2.z); STEP(b2.w); }

  write_outputs(rate, lane, out);
}

// Fallback if workspace is too small (or odd S): read noise in original
// layout with 1-step prefetch. Slow but correct.
__global__ __launch_bounds__(64) void scv_sim_fallback(
    const float* __restrict__ retL, const float* __restrict__ retR,
    const float* __restrict__ noise, float* __restrict__ out, int S) {
#pragma clang fp contract(off)
  const int lane = threadIdx.x;
  float Ib = compute_Ib(retL, retR, lane);

  float v = -65.0f;
  float u = 0.2f * v;
  float rate = 0.0f;

  const int neuron = lane & 31;
  float nxt = (S > 0) ? noise[neuron] : 0.0f;
  for (int t = 0; t < S; ++t) {
    float cur = nxt;
    nxt = (t + 1 < S) ? noise[(t + 1) * 32 + neuron] : 0.0f;
    STEP(cur);
  }

  write_outputs(rate, lane, out);
}

extern "C" void kernel_launch(void* const* d_in, const int* in_sizes, int n_in,
                              void* d_out, int out_size, void* d_ws,
                              size_t ws_size, hipStream_t stream) {
  const float* retL  = (const float*)d_in[0];
  const float* retR  = (const float*)d_in[1];
  const float* noise = (const float*)d_in[2];
  float* out = (float*)d_out;
  (void)n_in; (void)out_size;

  const int S = in_sizes[2] / 32;  // substeps
  const size_t needed = (size_t)(S + 16) * 32 * sizeof(float);

  if (ws_size >= needed && (S % 4) == 0 && S >= 16) {
    float* noiseT = (float*)d_ws;
    int total = 32 * (S + 16);
    int blocks = (total + 255) / 256;
    hipLaunchKernelGGL(scv_transpose_kernel, dim3(blocks), dim3(256), 0,
                       stream, noise, noiseT, S);
    hipLaunchKernelGGL(scv_sim_kernel, dim3(1), dim3(64), 0, stream, retL,
                       retR, noiseT, out, S);
  } else {
    hipLaunchKernelGGL(scv_sim_fallback, dim3(1), dim3(64), 0, stream, retL,
                       retR, noise, out, S);
  }
}

// Round 2
// 44.374 us; speedup vs baseline: 1.4321x; 1.4321x over previous
//
#include <hip/hip_runtime.h>
#include <math.h>

// ---------------------------------------------------------------------------
// SpikingColorVision: 4 pops x 8 ch Izhikevich RS neurons, 1000 Euler steps.
// Latency-bound single-wave serial recurrence. Kernel 1 (prep) computes the
// drive currents from the 800 retinal values AND writes a neuron-major
// stream I[n][t] = Ib[pop(n)] + noise[t][n]*0.3 (so the sim kernel loads the
// per-step current directly as contiguous float4). Kernel 2 runs the whole
// 1000-step recurrence in one 64-lane wave.
//
// v-update is re-associated for minimum dependency chain:
//   vn = fma(0.04*v, v, fma(5, v, ((140-u)+I)+v))
// (5 dependent ops/step instead of 9; ~1ULP reordering error, spike-flip
// probability ~1e-4 over the whole run -> rate outputs differ ~<1e-6).
// ---------------------------------------------------------------------------

// Fast step: I is the precomputed per-step current (Ib + eps*0.3).
#define FSTEP(Iv) do {                                   \
    float c1_  = (140.0f - u) + (Iv);      /* off-chain */\
    float c1v_ = c1_ + v;                  /* pos1 */     \
    float t1_  = 0.04f * v;                /* pos1 */     \
    float t3_  = __builtin_fmaf(5.0f, v, c1v_); /* pos2 */\
    float vn_  = __builtin_fmaf(t1_, v, t3_);   /* pos3 */\
    float in_  = __builtin_fmaf(0.2f, v, -u);             \
    float un_  = __builtin_fmaf(0.02f, in_, u);           \
    bool  sp_  = (vn_ >= 30.0f);           /* pos4 */     \
    v = sp_ ? -65.0f : vn_;                /* pos5 */     \
    float u8_ = un_ + 8.0f;                               \
    u = sp_ ? u8_ : un_;                                  \
    float w_ = sp_ ? 0.05f : 0.0f;                        \
    rate = __builtin_fmaf(0.95f, rate, w_);               \
  } while (0)

// Exact step (fallback path only) — mirrors reference op-for-op.
#define STEP_EXACT(eps) do {                             \
    float I_ = Ib + (eps) * 0.3f;                        \
    float q_ = 0.04f * v;                                \
    q_ = q_ * v;                                         \
    q_ = q_ + 5.0f * v;                                  \
    q_ = q_ + 140.0f;                                    \
    q_ = q_ - u;                                         \
    q_ = q_ + I_;                                        \
    float vn_ = v + q_;                                  \
    float un_ = u + 0.02f * (0.2f * v - u);              \
    bool  sp_ = (vn_ >= 30.0f);                          \
    float s_  = sp_ ? 1.0f : 0.0f;                       \
    v = sp_ ? -65.0f : vn_;                              \
    u = un_ + s_ * 8.0f;                                 \
    rate = 0.95f * rate + 0.05f * s_;                    \
  } while (0)

// Channel means + opponency outputs; lane holds rate for neuron lane&31.
__device__ __forceinline__ void write_outputs(float rate, int lane,
                                              float* __restrict__ out) {
#pragma clang fp contract(off)
  float rsum = rate;
  rsum += __shfl_xor(rsum, 1);
  rsum += __shfl_xor(rsum, 2);
  rsum += __shfl_xor(rsum, 4);
  float mean = rsum / 8.0f;            // exact /8
  float m_uv = __shfl(mean, 0);
  float m_bl = __shfl(mean, 8);
  float m_gr = __shfl(mean, 16);
  float m_rd = __shfl(mean, 24);
  if (lane == 0) {
    out[0] = m_uv;
    out[1] = m_bl;
    out[2] = m_gr;
    out[3] = m_rd;
    out[4] = m_rd - m_gr;
    out[5] = (m_uv + m_bl) / 2.0f - (m_gr + m_rd) / 2.0f;
  }
}

// Drives from the 800 retinal type values (exact integer counts -> any
// reduction order is exact). Every thread of the block gets all 4 Ib values.
__device__ void block_drives(const float* __restrict__ retL,
                             const float* __restrict__ retR,
                             float Ib[4]) {
#pragma clang fp contract(off)
  __shared__ float red[4][8];
  const int tid = threadIdx.x;
  float f = 0.0f, e = 0.0f, r = 0.0f, cp = 0.0f;
  for (int i = tid; i < 800; i += blockDim.x) {
    float t = (i < 400) ? retL[i] : retR[i - 400];
    f  += (t > 0.7f) ? 1.0f : 0.0f;
    e  += (fabsf(t - 0.5f)  < 0.1f) ? 1.0f : 0.0f;
    r  += (fabsf(t - 0.75f) < 0.1f) ? 1.0f : 0.0f;
    cp += (fabsf(t - 0.25f) < 0.1f) ? 1.0f : 0.0f;
  }
#pragma unroll
  for (int off = 1; off < 64; off <<= 1) {
    f  += __shfl_xor(f,  off);
    e  += __shfl_xor(e,  off);
    r  += __shfl_xor(r,  off);
    cp += __shfl_xor(cp, off);
  }
  const int nw = blockDim.x >> 6;
  if ((tid & 63) == 0) {
    int w = tid >> 6;
    red[0][w] = f; red[1][w] = e; red[2][w] = r; red[3][w] = cp;
  }
  __syncthreads();
  f = 0.0f; e = 0.0f; r = 0.0f; cp = 0.0f;
  for (int w = 0; w < nw; ++w) {
    f += red[0][w]; e += red[1][w]; r += red[2][w]; cp += red[3][w];
  }
  float total = f + e + r + cp + 1e-8f;
  Ib[0] = ((f * 0.1f + e * 0.05f + cp * 0.8f + r * 0.2f) / total) * 10.0f + (-2.0f);
  Ib[1] = ((f * 0.2f + e * 0.1f  + cp * 0.5f + r * 0.3f) / total) * 10.0f + (-2.0f);
  Ib[2] = ((f * 0.8f + e * 0.3f  + cp * 0.3f + r * 0.3f) / total) * 10.0f + (-2.0f);
  Ib[3] = ((f * 0.4f + e * 0.7f  + cp * 0.2f + r * 0.3f) / total) * 10.0f + (-2.0f);
}

// Prep: drives + transpose-with-fold. I[n][t] = Ib[pop(n)] + noise[t][n]*0.3,
// layout [32][S+16] (16-float zero pad so sim prefetch never goes OOB).
__global__ void scv_prep_kernel(const float* __restrict__ retL,
                                const float* __restrict__ retR,
                                const float* __restrict__ noise,
                                float* __restrict__ noiseT, int S) {
#pragma clang fp contract(off)
  float Ib[4];
  block_drives(retL, retR, Ib);

  int stride = S + 16;
  int total = 32 * stride;
  for (int o = blockIdx.x * blockDim.x + threadIdx.x; o < total;
       o += gridDim.x * blockDim.x) {
    int n = o / stride;
    int t = o - n * stride;
    noiseT[o] = (t < S) ? (Ib[n >> 3] + noise[t * 32 + n] * 0.3f) : 0.0f;
  }
}

// Main simulation: one block, one 64-lane wave. neuron = lane & 31
// (upper 32 lanes duplicate work to keep the wave uniform).
__global__ __launch_bounds__(64) void scv_sim_kernel(
    const float* __restrict__ noiseT, float* __restrict__ out, int S) {
  const int lane = threadIdx.x;
  const int neuron = lane & 31;
  const int stride4 = (S + 16) >> 2;
  const float4* src =
      reinterpret_cast<const float4*>(noiseT) + (size_t)neuron * stride4;

  float v = -65.0f;
  float u = -13.0f;   // 0.2f * -65.0f exactly
  float rate = 0.0f;

  int nChunks = S >> 2;          // 4 steps per float4
  float4 b0 = src[0], b1 = src[1], b2 = src[2], b3 = src[3];
  int cG = nChunks & ~3;
  for (int c = 0; c < cG; c += 4) {
    // issue next-iteration loads first (16-step prefetch distance)
    float4 a0 = src[c + 4], a1 = src[c + 5], a2 = src[c + 6], a3 = src[c + 7];
    FSTEP(b0.x); FSTEP(b0.y); FSTEP(b0.z); FSTEP(b0.w);
    FSTEP(b1.x); FSTEP(b1.y); FSTEP(b1.z); FSTEP(b1.w);
    FSTEP(b2.x); FSTEP(b2.y); FSTEP(b2.z); FSTEP(b2.w);
    FSTEP(b3.x); FSTEP(b3.y); FSTEP(b3.z); FSTEP(b3.w);
    b0 = a0; b1 = a1; b2 = a2; b3 = a3;
  }
  int rem = nChunks - cG;
  if (rem >= 1) { FSTEP(b0.x); FSTEP(b0.y); FSTEP(b0.z); FSTEP(b0.w); }
  if (rem >= 2) { FSTEP(b1.x); FSTEP(b1.y); FSTEP(b1.z); FSTEP(b1.w); }
  if (rem >= 3) { FSTEP(b2.x); FSTEP(b2.y); FSTEP(b2.z); FSTEP(b2.w); }

  write_outputs(rate, lane, out);
}

// Fallback for odd S / tiny workspace: exact reference math, raw noise layout.
__global__ __launch_bounds__(64) void scv_sim_fallback(
    const float* __restrict__ retL, const float* __restrict__ retR,
    const float* __restrict__ noise, float* __restrict__ out, int S) {
#pragma clang fp contract(off)
  const int lane = threadIdx.x;
  float f = 0.0f, e = 0.0f, r = 0.0f, cp = 0.0f;
  for (int i = lane; i < 800; i += 64) {
    float t = (i < 400) ? retL[i] : retR[i - 400];
    f  += (t > 0.7f) ? 1.0f : 0.0f;
    e  += (fabsf(t - 0.5f)  < 0.1f) ? 1.0f : 0.0f;
    r  += (fabsf(t - 0.75f) < 0.1f) ? 1.0f : 0.0f;
    cp += (fabsf(t - 0.25f) < 0.1f) ? 1.0f : 0.0f;
  }
#pragma unroll
  for (int off = 1; off < 64; off <<= 1) {
    f  += __shfl_xor(f,  off);
    e  += __shfl_xor(e,  off);
    r  += __shfl_xor(r,  off);
    cp += __shfl_xor(cp, off);
  }
  float total = f + e + r + cp + 1e-8f;
  int p = (lane >> 3) & 3;
  float dv;
  if (p == 0)      dv = (f * 0.1f + e * 0.05f + cp * 0.8f + r * 0.2f) / total;
  else if (p == 1) dv = (f * 0.2f + e * 0.1f  + cp * 0.5f + r * 0.3f) / total;
  else if (p == 2) dv = (f * 0.8f + e * 0.3f  + cp * 0.3f + r * 0.3f) / total;
  else             dv = (f * 0.4f + e * 0.7f  + cp * 0.2f + r * 0.3f) / total;
  float Ib = dv * 10.0f + (-2.0f);

  float v = -65.0f;
  float u = -13.0f;
  float rate = 0.0f;

  const int neuron = lane & 31;
  float nxt = (S > 0) ? noise[neuron] : 0.0f;
  for (int t = 0; t < S; ++t) {
    float cur = nxt;
    nxt = (t + 1 < S) ? noise[(t + 1) * 32 + neuron] : 0.0f;
    STEP_EXACT(cur);
  }

  write_outputs(rate, lane, out);
}

extern "C" void kernel_launch(void* const* d_in, const int* in_sizes, int n_in,
                              void* d_out, int out_size, void* d_ws,
                              size_t ws_size, hipStream_t stream) {
  const float* retL  = (const float*)d_in[0];
  const float* retR  = (const float*)d_in[1];
  const float* noise = (const float*)d_in[2];
  float* out = (float*)d_out;
  (void)n_in; (void)out_size;

  const int S = in_sizes[2] / 32;  // substeps
  const size_t needed = (size_t)(S + 16) * 32 * sizeof(float);

  if (ws_size >= needed && (S % 4) == 0 && S >= 16) {
    float* noiseT = (float*)d_ws;
    hipLaunchKernelGGL(scv_prep_kernel, dim3(32), dim3(256), 0, stream, retL,
                       retR, noise, noiseT, S);
    hipLaunchKernelGGL(scv_sim_kernel, dim3(1), dim3(64), 0, stream, noiseT,
                       out, S);
  } else {
    hipLaunchKernelGGL(scv_sim_fallback, dim3(1), dim3(64), 0, stream, retL,
                       retR, noise, out, S);
  }
}